// Round 9
// baseline (684.920 us; speedup 1.0000x reference)
//
#include <hip/hip_runtime.h>
#include <hip/hip_bf16.h>
#include <math.h>

constexpr int B_ = 128, N_ = 4096, E_ = 65536, T_ = 262144;

typedef __attribute__((ext_vector_type(8))) __bf16 bf16x8;
typedef __attribute__((ext_vector_type(4))) float f32x4;
typedef __hip_bfloat16 bf16;

__device__ __forceinline__ float silu_f(float x){ return x / (1.0f + __expf(-x)); }
__device__ __forceinline__ float bf2f(bf16 v){ return __bfloat162float(v); }
__device__ __forceinline__ bf16  f2bf(float v){ return __float2bfloat16(v); }
__device__ __forceinline__ float bfx(bf16x8 v, int j){ __bf16 t = v[j]; return (float)t; }
__device__ __forceinline__ int   swz(int row, int col){ return col ^ ((row & 7) << 3); }

// ================= CSR build =================
__global__ void hist2_kernel(const int* __restrict__ ji, const int* __restrict__ eidst,
                             int* __restrict__ cnt_ji, int* __restrict__ cnt_dst){
  int i = blockIdx.x*256 + threadIdx.x;
  if(i < T_) atomicAdd(&cnt_ji[ji[i]], 1);
  else       atomicAdd(&cnt_dst[eidst[i - T_]], 1);
}

// fill + tprep fused: triplet lane computes its CSR slot AND the Chebyshev basis (bf16)
__global__ __launch_bounds__(256) void fill2t_kernel(const int* __restrict__ ji, const int* __restrict__ kj,
                                                     const int* __restrict__ eidst, const float* __restrict__ vec,
                                                     int* __restrict__ cur_ji, int* __restrict__ kj_s,
                                                     bf16* __restrict__ cbf_s,
                                                     int* __restrict__ cur_dst, int* __restrict__ list_dst){
  int i = blockIdx.x*256 + threadIdx.x;
  if(i < T_){
    int a = ji[i], b = kj[i];
    int p = atomicAdd(&cur_ji[a], 1);
    kj_s[p] = b;
    float ax = vec[a*3], ay = vec[a*3+1], az = vec[a*3+2];
    float bx = vec[b*3], by = vec[b*3+1], bz = vec[b*3+2];
    float dot = ax*bx + ay*by + az*bz;
    float na = sqrtf(ax*ax + ay*ay + az*az);
    float nb = sqrtf(bx*bx + by*by + bz*bz);
    float x = dot / (na*nb + 1e-9f);
    x = fminf(fmaxf(x, -1.0f + 1e-6f), 1.0f - 1e-6f);
    float c[16];
    c[0] = 1.0f; c[1] = x;
    float x2 = 2.0f * x;
    #pragma unroll
    for(int s = 2; s < 16; s++) c[s] = x2*c[s-1] - c[s-2];
    bf16x8 o0, o1;
    #pragma unroll
    for(int j = 0; j < 8; j++){ o0[j] = (__bf16)c[j]; o1[j] = (__bf16)c[8+j]; }
    *(bf16x8*)&cbf_s[(size_t)p*16]     = o0;
    *(bf16x8*)&cbf_s[(size_t)p*16 + 8] = o1;
  } else {
    int e = i - T_;
    int p = atomicAdd(&cur_dst[eidst[e]], 1);
    list_dst[p] = e;
  }
}

// hierarchical scan: A = per-1024-chunk sums, B = scan chunk sums, C = apply.
__global__ __launch_bounds__(256) void scanA_kernel(const int* __restrict__ cnt_ji, const int* __restrict__ cnt_dst,
                                                    int* __restrict__ bsum){
  int blk = blockIdx.x;
  const int* src = (blk < 64) ? cnt_ji : cnt_dst;
  int base = (blk < 64) ? blk*1024 : (blk - 64)*1024;
  int t = threadIdx.x;
  int4 v = *(const int4*)&src[base + t*4];
  int s = v.x + v.y + v.z + v.w;
  #pragma unroll
  for(int d = 1; d < 64; d <<= 1) s += __shfl_xor(s, d);
  __shared__ int ws[4];
  if((t & 63) == 0) ws[t >> 6] = s;
  __syncthreads();
  if(t == 0) bsum[blk] = ws[0] + ws[1] + ws[2] + ws[3];
}
__global__ __launch_bounds__(128) void scanB_kernel(const int* __restrict__ bsum, int* __restrict__ boff){
  __shared__ int sh[68];
  int t = threadIdx.x;
  if(t < 68) sh[t] = bsum[t];
  __syncthreads();
  if(t == 0){
    int run = 0;
    for(int i = 0; i < 64; i++){ boff[i] = run; run += sh[i]; }
    run = 0;
    for(int i = 64; i < 68; i++){ boff[i] = run; run += sh[i]; }
  }
}
__global__ __launch_bounds__(256) void scanC_kernel(const int* __restrict__ cnt_ji, const int* __restrict__ cnt_dst,
                                                    const int* __restrict__ boff,
                                                    int* __restrict__ off_ji, int* __restrict__ cur_ji,
                                                    int* __restrict__ off_dst, int* __restrict__ cur_dst){
  int blk = blockIdx.x;
  const int* src; int* offs; int* cur; int base;
  if(blk < 64){ src = cnt_ji; offs = off_ji; cur = cur_ji; base = blk*1024; }
  else        { src = cnt_dst; offs = off_dst; cur = cur_dst; base = (blk - 64)*1024; }
  int t = threadIdx.x, lane = t & 63, w = t >> 6;
  int4 v = *(const int4*)&src[base + t*4];
  int s4 = v.x + v.y + v.z + v.w;
  int x = s4;
  #pragma unroll
  for(int d = 1; d < 64; d <<= 1){ int u = __shfl_up(x, d); if(lane >= d) x += u; }
  __shared__ int ws[4];
  if(lane == 63) ws[w] = x;
  __syncthreads();
  int wo = 0;
  for(int i = 0; i < w; i++) wo += ws[i];
  int o0 = boff[blk] + wo + (x - s4);
  int4 oo;
  oo.x = o0; oo.y = o0 + v.x; oo.z = oo.y + v.y; oo.w = oo.z + v.z;
  *(int4*)&offs[base + t*4] = oo;
  *(int4*)&cur[base + t*4]  = oo;
  if(blk == 0 && t == 0){ off_ji[E_] = T_; off_dst[N_] = E_; }
}

// ================= geometry =================
__global__ void pos_kernel(const float* __restrict__ frac, const float* __restrict__ lengths,
                           const float* __restrict__ angles, float* __restrict__ pos){
  int i = blockIdx.x*256 + threadIdx.x;
  if(i >= N_) return;
  int b = i >> 5;
  const float d2r = 0.017453292519943295f;
  float La = lengths[b*3+0], Lb = lengths[b*3+1], Lc = lengths[b*3+2];
  float al = angles[b*3+0]*d2r, be = angles[b*3+1]*d2r, ga = angles[b*3+2]*d2r;
  float ca = cosf(al), cb = cosf(be), cg = cosf(ga), sg = sinf(ga);
  float cx = cb, cy = (ca - cb*cg) / sg;
  float cz = sqrtf(fmaxf(1.0f - cx*cx - cy*cy, 1e-8f));
  float l00 = La, l10 = Lb*cg, l11 = Lb*sg, l20 = Lc*cx, l21 = Lc*cy, l22 = Lc*cz;
  float fx = frac[i*3], fy = frac[i*3+1], fz = frac[i*3+2];
  pos[i*3+0] = fx*l00 + fy*l10 + fz*l20;
  pos[i*3+1] = fy*l11 + fz*l21;
  pos[i*3+2] = fz*l22;
}

__global__ __launch_bounds__(256) void edge_kernel(const float* __restrict__ pos, const int* __restrict__ ei,
                                                   float* __restrict__ vec, bf16* __restrict__ rbf){
  int e = blockIdx.x*4 + (threadIdx.x >> 6);
  int lane = threadIdx.x & 63;
  int s = ei[e], d = ei[E_ + e];
  float vx = pos[d*3+0]-pos[s*3+0];
  float vy = pos[d*3+1]-pos[s*3+1];
  float vz = pos[d*3+2]-pos[s*3+2];
  float dd = sqrtf(vx*vx + vy*vy + vz*vz + 1e-12f);
  float dsc = dd * (1.0f/7.0f);
  float env = 0.0f;
  if(dsc < 1.0f){
    float d2 = dsc*dsc, d5 = d2*d2*dsc;
    env = 1.0f - 21.0f*d5 + 35.0f*d5*dsc - 15.0f*d5*d2;
  }
  float arg = (float)(lane+1) * 3.14159265358979f * dsc;
  rbf[(size_t)e*64 + lane] = f2bf(env * 0.5345224838248488f * sinf(arg) / dd);
  if(lane < 3){ vec[e*3+lane] = (lane==0) ? vx : (lane==1 ? vy : vz); }
}

// ================= weight transpose+convert =================
struct WDesc { const float* src; bf16* dst; int K; int shN; };
struct WPackAll { WDesc d[29]; };
__global__ __launch_bounds__(256) void wconv_kernel(WPackAll p){
  WDesc w = p.d[blockIdx.y];
  int idx = blockIdx.x*256 + threadIdx.x;
  int NN = 1 << w.shN;
  if(idx >= w.K * NN) return;
  int k = idx >> w.shN, c = idx & (NN - 1);
  w.dst[(size_t)c * w.K + k] = f2bf(w.src[idx]);
}

// ================= h init =================
__global__ __launch_bounds__(128) void h0_kernel(const float* __restrict__ emb, const int* __restrict__ types,
                                                 const float* __restrict__ noise, const float* __restrict__ Whz,
                                                 float* __restrict__ h, bf16* __restrict__ hbf){
  __shared__ float arow[129];
  int i = blockIdx.x;
  int c = threadIdx.x;
  arow[c] = emb[(size_t)types[i]*128 + c];
  if(c == 0) arow[128] = noise[i >> 5];
  __syncthreads();
  float acc = 0.f;
  for(int k = 0; k < 129; k++) acc += arow[k] * Whz[(size_t)k*128 + c];
  float v = silu_f(acc);
  h[(size_t)i*128 + c] = v;
  hbf[(size_t)i*128 + c] = f2bf(v);
}

// ================= MFMA cores =================
template<int KK, int FM>
__device__ __forceinline__ void kloop(const bf16* __restrict__ A, const bf16* __restrict__ W,
                                      int rowA0, int colW0, int lr, int lk, f32x4 (*acc)[4])
{
  #pragma unroll
  for(int k0 = 0; k0 < KK; k0 += 32){
    bf16x8 af[FM], bv[4];
    #pragma unroll
    for(int fm = 0; fm < FM; fm++)
      af[fm] = *(const bf16x8*)(A + (size_t)(rowA0 + fm*16 + lr)*KK + k0 + lk*8);
    #pragma unroll
    for(int fn = 0; fn < 4; fn++)
      bv[fn] = *(const bf16x8*)(W + (size_t)(colW0 + fn*16 + lr)*KK + k0 + lk*8);
    #pragma unroll
    for(int fm = 0; fm < FM; fm++)
      #pragma unroll
      for(int fn = 0; fn < 4; fn++)
        acc[fm][fn] = __builtin_amdgcn_mfma_f32_16x16x32_bf16(af[fm], bv[fn], acc[fm][fn], 0, 0, 0);
  }
}

template<int FM>
__device__ __forceinline__ void kloop_lds(const __bf16* sA, const bf16* __restrict__ W,
                                          int rowL0, int colW0, int lr, int lk, f32x4 (*acc)[4])
{
  #pragma unroll
  for(int k0 = 0; k0 < 128; k0 += 32){
    bf16x8 af[FM], bv[4];
    #pragma unroll
    for(int fm = 0; fm < FM; fm++){
      int row = rowL0 + fm*16 + lr;
      af[fm] = *(const bf16x8*)&sA[row*128 + swz(row, k0 + lk*8)];
    }
    #pragma unroll
    for(int fn = 0; fn < 4; fn++)
      bv[fn] = *(const bf16x8*)(W + (size_t)(colW0 + fn*16 + lr)*128 + k0 + lk*8);
    #pragma unroll
    for(int fm = 0; fm < FM; fm++)
      #pragma unroll
      for(int fn = 0; fn < 4; fn++)
        acc[fm][fn] = __builtin_amdgcn_mfma_f32_16x16x32_bf16(af[fm], bv[fn], acc[fm][fn], 0, 0, 0);
  }
}

// shared epilogue piece: dual GEMM over sM + @Wdown, single LDS buffer (in place)
__device__ __forceinline__ void dd_tail(__bf16* sM, const bf16* __restrict__ Wm,
                                        const bf16* __restrict__ rbf, const bf16* __restrict__ Wr1,
                                        const bf16* __restrict__ Wd, bf16* __restrict__ xout,
                                        int row0, int wid, int wr, int wc, int lr, int lk)
{
  f32x4 acc[4][4];
  #pragma unroll
  for(int i = 0; i < 4; i++)
    #pragma unroll
    for(int j = 0; j < 4; j++) acc[i][j] = (f32x4){0.f,0.f,0.f,0.f};
  kloop_lds<4>(sM, Wm, wr*64, wc*64, lr, lk, acc);
  float sv[4][4][4];
  #pragma unroll
  for(int i = 0; i < 4; i++)
    #pragma unroll
    for(int j = 0; j < 4; j++){
      #pragma unroll
      for(int r = 0; r < 4; r++) sv[i][j][r] = silu_f(acc[i][j][r]);
      acc[i][j] = (f32x4){0.f,0.f,0.f,0.f};
    }
  kloop<64,4>(rbf, Wr1, row0 + wr*64, wc*64, lr, lk, acc);
  __syncthreads();               // all GEMM1 LDS reads done before overwrite
  #pragma unroll
  for(int fm = 0; fm < 4; fm++)
    #pragma unroll
    for(int fn = 0; fn < 4; fn++)
      #pragma unroll
      for(int r = 0; r < 4; r++){
        int row = wr*64 + fm*16 + lk*4 + r;
        int col = wc*64 + fn*16 + lr;
        sM[row*128 + swz(row, col)] = (__bf16)(sv[fm][fn][r] * acc[fm][fn][r]);
      }
  __syncthreads();
  // GEMM2: x = tmp @ Wdown
  f32x4 a2[2][4];
  #pragma unroll
  for(int i = 0; i < 2; i++)
    #pragma unroll
    for(int j = 0; j < 4; j++) a2[i][j] = (f32x4){0.f,0.f,0.f,0.f};
  kloop_lds<2>(sM, Wd, wid*32, 0, lr, lk, a2);
  #pragma unroll
  for(int fm = 0; fm < 2; fm++)
    #pragma unroll
    for(int fn = 0; fn < 4; fn++)
      #pragma unroll
      for(int r = 0; r < 4; r++){
        int row = wid*32 + fm*16 + lk*4 + r;
        int col = fn*16 + lr;
        xout[(size_t)(row0 + row)*64 + col] = f2bf(a2[fm][fn][r]);
      }
}

// ===== dd0_fused (b=0): m = silu(concat@Wedge) computed in-kernel, then dual GEMM + @Wdown =====
__global__ __launch_bounds__(256, 2) void dd0_fused(
    const bf16* __restrict__ hb, const bf16* __restrict__ rbf, const int* __restrict__ ei,
    const bf16* __restrict__ We /*[128][320]*/, bf16* __restrict__ m,
    const bf16* __restrict__ Wm, const bf16* __restrict__ Wr1,
    const bf16* __restrict__ Wd, bf16* __restrict__ xout)
{
  __shared__ __bf16 sM[128*128];
  const int tid = threadIdx.x;
  const int wid = tid >> 6, lane = tid & 63;
  const int wr = wid >> 1, wc = wid & 1;
  const int lr = lane & 15, lk = lane >> 4;
  const int row0 = blockIdx.x*128;
  const int e0 = row0 + wr*64;

  int esrc[4], edst[4];
  #pragma unroll
  for(int fm = 0; fm < 4; fm++){
    int e = e0 + fm*16 + lr;
    esrc[fm] = ei[e]; edst[fm] = ei[E_ + e];
  }
  f32x4 acc[4][4];
  #pragma unroll
  for(int i = 0; i < 4; i++)
    #pragma unroll
    for(int j = 0; j < 4; j++) acc[i][j] = (f32x4){0.f,0.f,0.f,0.f};
  #pragma unroll
  for(int ks = 0; ks < 10; ks++){
    const int k0 = ks*32;
    bf16x8 af[4], bv[4];
    #pragma unroll
    for(int fm = 0; fm < 4; fm++){
      const bf16* p;
      if(k0 < 128)      p = hb + (size_t)esrc[fm]*128 + k0;
      else if(k0 < 256) p = hb + (size_t)edst[fm]*128 + (k0 - 128);
      else              p = rbf + (size_t)(e0 + fm*16 + lr)*64 + (k0 - 256);
      af[fm] = *(const bf16x8*)(p + lk*8);
    }
    #pragma unroll
    for(int fn = 0; fn < 4; fn++)
      bv[fn] = *(const bf16x8*)(We + (size_t)(wc*64 + fn*16 + lr)*320 + k0 + lk*8);
    #pragma unroll
    for(int fm = 0; fm < 4; fm++)
      #pragma unroll
      for(int fn = 0; fn < 4; fn++)
        acc[fm][fn] = __builtin_amdgcn_mfma_f32_16x16x32_bf16(af[fm], bv[fn], acc[fm][fn], 0, 0, 0);
  }
  #pragma unroll
  for(int fm = 0; fm < 4; fm++)
    #pragma unroll
    for(int fn = 0; fn < 4; fn++)
      #pragma unroll
      for(int r = 0; r < 4; r++){
        int row = wr*64 + fm*16 + lk*4 + r;
        int col = wc*64 + fn*16 + lr;
        bf16 v = f2bf(silu_f(acc[fm][fn][r]));
        m[(size_t)(row0 + row)*128 + col] = v;
        sM[row*128 + swz(row, col)] = (__bf16)bf2f(v);
      }
  __syncthreads();
  dd_tail(sM, Wm, rbf, Wr1, Wd, xout, row0, wid, wr, wc, lr, lk);
}

// ===== dd_fused (b>=1): scat + dual GEMM + @Wdown, single LDS buffer =====
__global__ __launch_bounds__(256, 2) void dd_fused(
    bf16* __restrict__ m, const bf16* __restrict__ Wm,
    const bf16* __restrict__ rbf, const bf16* __restrict__ Wr1,
    const bf16* __restrict__ Wd, bf16* __restrict__ xout,
    const int* __restrict__ ei, const bf16* __restrict__ hs, const bf16* __restrict__ ht)
{
  __shared__ __bf16 sM[128*128];
  const int tid = threadIdx.x;
  const int wid = tid >> 6, lane = tid & 63;
  const int wr = wid >> 1, wc = wid & 1;
  const int lr = lane & 15, lk = lane >> 4;
  const int row0 = blockIdx.x*128;

  {
    int r = tid >> 1, c0 = (tid & 1)*64;
    int e = row0 + r;
    int s = ei[e], d = ei[E_ + e];
    #pragma unroll
    for(int j = 0; j < 8; j++){
      int col = c0 + j*8;
      bf16x8 vm = *(const bf16x8*)&m[(size_t)e*128 + col];
      bf16x8 va = *(const bf16x8*)&hs[(size_t)s*128 + col];
      bf16x8 vb = *(const bf16x8*)&ht[(size_t)d*128 + col];
      #pragma unroll
      for(int q = 0; q < 8; q++) vm[q] = (__bf16)(bfx(vm,q) + silu_f(bfx(va,q) + bfx(vb,q)));
      *(bf16x8*)&m[(size_t)e*128 + col] = vm;
      *(bf16x8*)&sM[r*128 + swz(r, col)] = vm;
    }
  }
  __syncthreads();
  dd_tail(sM, Wm, rbf, Wr1, Wd, xout, row0, wid, wr, wc, lr, lk);
}

// ===== wup_wa: m += silu(ts@Wup); tmp = silu(m@Wa)*(rbf@Wr2) — single LDS buffer =====
template<bool WRITEM>
__global__ __launch_bounds__(256, 2) void wup_wa(
    const bf16* __restrict__ ts, const bf16* __restrict__ Wu,
    bf16* __restrict__ m, const bf16* __restrict__ Wa,
    const bf16* __restrict__ rbf, const bf16* __restrict__ Wr2,
    bf16* __restrict__ tmp)
{
  __shared__ __bf16 sB[128*128];
  const int tid = threadIdx.x;
  const int wid = tid >> 6, lane = tid & 63;
  const int wr = wid >> 1, wc = wid & 1;
  const int lr = lane & 15, lk = lane >> 4;
  const int row0 = blockIdx.x*128;

  {
    int r = tid >> 1, c0 = (tid & 1)*64;
    #pragma unroll
    for(int j = 0; j < 8; j++){
      int col = c0 + j*8;
      bf16x8 vm = *(const bf16x8*)&m[(size_t)(row0 + r)*128 + col];
      *(bf16x8*)&sB[r*128 + swz(r, col)] = vm;
    }
  }
  __syncthreads();

  f32x4 acc[4][4];
  #pragma unroll
  for(int i = 0; i < 4; i++)
    #pragma unroll
    for(int j = 0; j < 4; j++) acc[i][j] = (f32x4){0.f,0.f,0.f,0.f};
  kloop<64,4>(ts, Wu, row0 + wr*64, wc*64, lr, lk, acc);

  // u = m + silu(.): in-place (each thread owns its (row,col) slots)
  #pragma unroll
  for(int fm = 0; fm < 4; fm++)
    #pragma unroll
    for(int fn = 0; fn < 4; fn++)
      #pragma unroll
      for(int r = 0; r < 4; r++){
        int row = wr*64 + fm*16 + lk*4 + r;
        int col = wc*64 + fn*16 + lr;
        float x = (float)sB[row*128 + swz(row, col)] + silu_f(acc[fm][fn][r]);
        if(WRITEM) m[(size_t)(row0 + row)*128 + col] = f2bf(x);
        sB[row*128 + swz(row, col)] = (__bf16)x;
      }
  __syncthreads();

  #pragma unroll
  for(int i = 0; i < 4; i++)
    #pragma unroll
    for(int j = 0; j < 4; j++) acc[i][j] = (f32x4){0.f,0.f,0.f,0.f};
  kloop_lds<4>(sB, Wa, wr*64, wc*64, lr, lk, acc);
  float sv[4][4][4];
  #pragma unroll
  for(int i = 0; i < 4; i++)
    #pragma unroll
    for(int j = 0; j < 4; j++){
      #pragma unroll
      for(int r = 0; r < 4; r++) sv[i][j][r] = silu_f(acc[i][j][r]);
      acc[i][j] = (f32x4){0.f,0.f,0.f,0.f};
    }
  kloop<64,4>(rbf, Wr2, row0 + wr*64, wc*64, lr, lk, acc);
  #pragma unroll
  for(int fm = 0; fm < 4; fm++)
    #pragma unroll
    for(int fn = 0; fn < 4; fn++)
      #pragma unroll
      for(int r = 0; r < 4; r++){
        int row = wr*64 + fm*16 + lk*4 + r;
        int col = wc*64 + fn*16 + lr;
        tmp[(size_t)(row0 + row)*128 + col] = f2bf(sv[fm][fn][r] * acc[fm][fn][r]);
      }
}

// ===== atom_fused: h += silu(a@Wh); then hs/ht (or hW on last iter) =====
template<bool LAST>
__global__ __launch_bounds__(256, 2) void atom_fused(
    const bf16* __restrict__ a, const bf16* __restrict__ Wh,
    float* __restrict__ h,
    const bf16* __restrict__ Wst, bf16* __restrict__ hs, bf16* __restrict__ ht,
    const bf16* __restrict__ Wo, float* __restrict__ hW)
{
  __shared__ __bf16 sH[128*128];
  const int tid = threadIdx.x;
  const int wid = tid >> 6, lane = tid & 63;
  const int wr = wid >> 1, wc = wid & 1;
  const int lr = lane & 15, lk = lane >> 4;
  const int row0 = blockIdx.x*128;

  f32x4 acc[4][4];
  #pragma unroll
  for(int i = 0; i < 4; i++)
    #pragma unroll
    for(int j = 0; j < 4; j++) acc[i][j] = (f32x4){0.f,0.f,0.f,0.f};
  kloop<128,4>(a, Wh, row0 + wr*64, wc*64, lr, lk, acc);

  #pragma unroll
  for(int fm = 0; fm < 4; fm++)
    #pragma unroll
    for(int fn = 0; fn < 4; fn++)
      #pragma unroll
      for(int r = 0; r < 4; r++){
        int row = wr*64 + fm*16 + lk*4 + r;
        int col = wc*64 + fn*16 + lr;
        size_t off = (size_t)(row0 + row)*128 + col;
        float x = h[off] + silu_f(acc[fm][fn][r]);
        h[off] = x;
        sH[row*128 + swz(row, col)] = (__bf16)x;
      }
  __syncthreads();

  if(!LAST){
    #pragma unroll
    for(int i = 0; i < 4; i++)
      #pragma unroll
      for(int j = 0; j < 4; j++) acc[i][j] = (f32x4){0.f,0.f,0.f,0.f};
    kloop_lds<4>(sH, Wst, wr*64, wc*64, lr, lk, acc);
    #pragma unroll
    for(int fm = 0; fm < 4; fm++)
      #pragma unroll
      for(int fn = 0; fn < 4; fn++)
        #pragma unroll
        for(int r = 0; r < 4; r++){
          int row = wr*64 + fm*16 + lk*4 + r;
          int col = wc*64 + fn*16 + lr;
          hs[(size_t)(row0 + row)*128 + col] = f2bf(acc[fm][fn][r]);
        }
    #pragma unroll
    for(int i = 0; i < 4; i++)
      #pragma unroll
      for(int j = 0; j < 4; j++) acc[i][j] = (f32x4){0.f,0.f,0.f,0.f};
    kloop_lds<4>(sH, Wst + 128*128, wr*64, wc*64, lr, lk, acc);
    #pragma unroll
    for(int fm = 0; fm < 4; fm++)
      #pragma unroll
      for(int fn = 0; fn < 4; fn++)
        #pragma unroll
        for(int r = 0; r < 4; r++){
          int row = wr*64 + fm*16 + lk*4 + r;
          int col = wc*64 + fn*16 + lr;
          ht[(size_t)(row0 + row)*128 + col] = f2bf(acc[fm][fn][r]);
        }
  } else {
    #pragma unroll
    for(int i = 0; i < 4; i++)
      #pragma unroll
      for(int j = 0; j < 4; j++) acc[i][j] = (f32x4){0.f,0.f,0.f,0.f};
    kloop_lds<4>(sH, Wo, wr*64, wc*64, lr, lk, acc);
    #pragma unroll
    for(int fm = 0; fm < 4; fm++)
      #pragma unroll
      for(int fn = 0; fn < 4; fn++)
        #pragma unroll
        for(int r = 0; r < 4; r++){
          int row = wr*64 + fm*16 + lk*4 + r;
          int col = wc*64 + fn*16 + lr;
          hW[(size_t)(row0 + row)*128 + col] = acc[fm][fn][r];
        }
  }
}

// ================= triplet segsum: lane-parallel index prefetch + 4-wide gather batch =================
__global__ __launch_bounds__(256) void tsum_kernel(const int* __restrict__ offs, const int* __restrict__ kj_s,
                                                   const bf16* __restrict__ cbf_s, const bf16* __restrict__ x,
                                                   const float* __restrict__ Wc, bf16* __restrict__ ts){
  int e = blockIdx.x*4 + (threadIdx.x >> 6);
  int lane = threadIdx.x & 63;
  float wcv[16];
  #pragma unroll
  for(int s = 0; s < 16; s++) wcv[s] = Wc[s*64 + lane];
  float acc = 0.f;
  int b0 = offs[e], b1 = offs[e+1];
  int base = b0;
  while(base < b1){
    int cnt = min(b1 - base, 64);
    // one coalesced load of up to 64 triplet indices; inner loop gets k via shfl (no memory dep)
    int myk = (lane < cnt) ? kj_s[base + lane] : 0;
    int j = 0;
    for(; j + 4 <= cnt; j += 4){
      int k0 = __shfl(myk, j+0), k1 = __shfl(myk, j+1);
      int k2 = __shfl(myk, j+2), k3 = __shfl(myk, j+3);
      // 4 independent gathers in flight
      float x0 = bf2f(x[(size_t)k0*64 + lane]);
      float x1 = bf2f(x[(size_t)k1*64 + lane]);
      float x2 = bf2f(x[(size_t)k2*64 + lane]);
      float x3 = bf2f(x[(size_t)k3*64 + lane]);
      float cw[4];
      #pragma unroll
      for(int u = 0; u < 4; u++){
        bf16x8 ca = *(const bf16x8*)&cbf_s[(size_t)(base + j + u)*16];
        bf16x8 cb = *(const bf16x8*)&cbf_s[(size_t)(base + j + u)*16 + 8];
        float s = 0.f;
        #pragma unroll
        for(int q = 0; q < 8; q++) s += bfx(ca,q)*wcv[q] + bfx(cb,q)*wcv[8+q];
        cw[u] = s;
      }
      acc += x0*cw[0] + x1*cw[1] + x2*cw[2] + x3*cw[3];
    }
    for(; j < cnt; j++){
      int k = __shfl(myk, j);
      bf16x8 ca = *(const bf16x8*)&cbf_s[(size_t)(base + j)*16];
      bf16x8 cb = *(const bf16x8*)&cbf_s[(size_t)(base + j)*16 + 8];
      float s = 0.f;
      #pragma unroll
      for(int q = 0; q < 8; q++) s += bfx(ca,q)*wcv[q] + bfx(cb,q)*wcv[8+q];
      acc += bf2f(x[(size_t)k*64 + lane]) * s;
    }
    base += cnt;
  }
  ts[(size_t)e*64 + lane] = f2bf(acc);
}

// ================= edge->atom segsum =================
__global__ __launch_bounds__(256) void asum_kernel(const int* __restrict__ offs, const int* __restrict__ list,
                                                   const bf16* __restrict__ buf, bf16* __restrict__ a){
  int g = blockIdx.x*256 + threadIdx.x;
  int i = g >> 4, c8 = g & 15;
  float acc[8];
  #pragma unroll
  for(int j = 0; j < 8; j++) acc[j] = 0.f;
  int b0 = offs[i], b1 = offs[i+1];
  for(int idx = b0; idx < b1; ++idx){
    bf16x8 v = *(const bf16x8*)&buf[(size_t)list[idx]*128 + c8*8];
    #pragma unroll
    for(int j = 0; j < 8; j++) acc[j] += bfx(v,j);
  }
  bf16x8 o;
  #pragma unroll
  for(int j = 0; j < 8; j++) o[j] = (__bf16)acc[j];
  *(bf16x8*)&a[(size_t)i*128 + c8*8] = o;
}

// ================= fused readout MLP =================
__global__ __launch_bounds__(256) void mlp_kernel(const float* __restrict__ hW, const int* __restrict__ numat,
    const float* __restrict__ W0, const float* __restrict__ b0,
    const float* __restrict__ W1, const float* __restrict__ b1,
    const float* __restrict__ W2, const float* __restrict__ b2,
    float* __restrict__ out)
{
  __shared__ float zs[128], x0[256], x1[256];
  int b = blockIdx.x, t = threadIdx.x;
  if(t < 128){
    float s = 0.f;
    #pragma unroll 4
    for(int i = 0; i < 32; i++) s += hW[((size_t)(b*32 + i))*128 + t];
    zs[t] = s / (float)numat[b];
  }
  __syncthreads();
  {
    float acc = b0[t];
    for(int k = 0; k < 128; k++) acc += zs[k] * W0[(size_t)k*256 + t];
    x0[t] = fmaxf(acc, 0.f);
  }
  __syncthreads();
  {
    float acc = b1[t];
    for(int k = 0; k < 256; k++) acc += x0[k] * W1[(size_t)k*256 + t];
    x1[t] = fmaxf(acc, 0.f);
  }
  __syncthreads();
  if(t < 230){
    float acc = b2[t];
    for(int k = 0; k < 256; k++) acc += x1[k] * W2[(size_t)k*230 + t];
    out[(size_t)b*230 + t] = acc;
  }
}

extern "C" void kernel_launch(void* const* d_in, const int* in_sizes, int n_in,
                              void* d_out, int out_size, void* d_ws, size_t ws_size,
                              hipStream_t stream)
{
  const float* noise   = (const float*)d_in[0];
  const float* frac    = (const float*)d_in[1];
  const float* lengths = (const float*)d_in[2];
  const float* angles  = (const float*)d_in[3];
  const int*   types   = (const int*)d_in[4];
  const int*   numat   = (const int*)d_in[5];
  const int*   ei      = (const int*)d_in[6];
  const int*   ji      = (const int*)d_in[7];
  const int*   kj      = (const int*)d_in[8];
  const float* emb     = (const float*)d_in[9];
  const float* Whz     = (const float*)d_in[10];
  const float* Wedge   = (const float*)d_in[11];
  const float* Wm      = (const float*)d_in[12];
  const float* Wr1     = (const float*)d_in[13];
  const float* Wdown   = (const float*)d_in[14];
  const float* Wcbf    = (const float*)d_in[15];
  const float* Wup     = (const float*)d_in[16];
  const float* Wa      = (const float*)d_in[17];
  const float* Wr2     = (const float*)d_in[18];
  const float* Wh      = (const float*)d_in[19];
  const float* Wsw     = (const float*)d_in[20];
  const float* Wtw     = (const float*)d_in[21];
  const float* Wout    = (const float*)d_in[22];
  const float* Wfc0    = (const float*)d_in[23];
  const float* bfc0    = (const float*)d_in[24];
  const float* Wfc1    = (const float*)d_in[25];
  const float* bfc1    = (const float*)d_in[26];
  const float* Wfc2    = (const float*)d_in[27];
  const float* bfc2    = (const float*)d_in[28];
  float* out = (float*)d_out;

  char* base = (char*)d_ws;
  size_t oo = 0;
  auto ab = [&](size_t bytes)->void*{ void* p = base + oo; oo += bytes; oo = (oo + 63) & ~(size_t)63; return p; };

  float* pos   = (float*)ab((size_t)N_*3*4);
  float* vec   = (float*)ab((size_t)E_*3*4);
  bf16*  rbf   = (bf16*) ab((size_t)E_*64*2);
  bf16*  cbf_s = (bf16*) ab((size_t)T_*16*2);
  int*   kj_s  = (int*)  ab((size_t)T_*4);
  float* h     = (float*)ab((size_t)N_*128*4);
  bf16*  hbf   = (bf16*) ab((size_t)N_*128*2);
  bf16*  m     = (bf16*) ab((size_t)E_*128*2);
  bf16*  tmp   = (bf16*) ab((size_t)E_*128*2);
  bf16*  ts    = (bf16*) ab((size_t)E_*64*2);
  bf16*  xbuf  = (bf16*) ab((size_t)E_*64*2);
  bf16*  a     = (bf16*) ab((size_t)N_*128*2);
  bf16*  hsb   = (bf16*) ab((size_t)N_*128*2);
  bf16*  htb   = (bf16*) ab((size_t)N_*128*2);
  float* hW    = (float*)ab((size_t)N_*128*4);

  bf16* WedgeT = (bf16*)ab(320*128*2);
  bf16* WmT    = (bf16*)ab((size_t)3*128*128*2);
  bf16* Wr1T   = (bf16*)ab((size_t)3*128*64*2);
  bf16* WdownT = (bf16*)ab((size_t)3*64*128*2);
  bf16* WupT   = (bf16*)ab((size_t)3*128*64*2);
  bf16* WaT    = (bf16*)ab((size_t)3*128*128*2);
  bf16* Wr2T   = (bf16*)ab((size_t)3*128*64*2);
  bf16* WhT    = (bf16*)ab((size_t)3*128*128*2);
  bf16* WstT   = (bf16*)ab((size_t)3*2*128*128*2);
  bf16* WoutT  = (bf16*)ab(128*128*2);

  int* cnt_ji   = (int*)ab((size_t)(E_ + N_)*4);
  int* cnt_dst  = cnt_ji + E_;
  int* off_ji   = (int*)ab((size_t)(E_+1)*4);
  int* cur_ji   = (int*)ab((size_t)E_*4);
  int* off_dst  = (int*)ab((size_t)(N_+1)*4);
  int* cur_dst  = (int*)ab((size_t)N_*4);
  int* list_dst = (int*)ab((size_t)E_*4);
  int* bsum     = (int*)ab(68*4);
  int* boff     = (int*)ab(68*4);

  // ---- weight conversion (single dispatch) ----
  WPackAll p{};
  {
    int i = 0;
    p.d[i++] = {Wedge, WedgeT, 320, 7};
    for(int b=0;b<3;b++) p.d[i++] = {Wm   + (size_t)b*128*128, WmT   + (size_t)b*128*128, 128, 7};
    for(int b=0;b<3;b++) p.d[i++] = {Wr1  + (size_t)b*64*128,  Wr1T  + (size_t)b*128*64,   64, 7};
    for(int b=0;b<3;b++) p.d[i++] = {Wdown+ (size_t)b*128*64,  WdownT+ (size_t)b*64*128,  128, 6};
    for(int b=0;b<3;b++) p.d[i++] = {Wup  + (size_t)b*64*128,  WupT  + (size_t)b*128*64,   64, 7};
    for(int b=0;b<3;b++) p.d[i++] = {Wa   + (size_t)b*128*128, WaT   + (size_t)b*128*128, 128, 7};
    for(int b=0;b<3;b++) p.d[i++] = {Wr2  + (size_t)b*64*128,  Wr2T  + (size_t)b*128*64,   64, 7};
    for(int b=0;b<3;b++) p.d[i++] = {Wh   + (size_t)b*128*128, WhT   + (size_t)b*128*128, 128, 7};
    for(int b=0;b<3;b++) p.d[i++] = {Wsw  + (size_t)b*128*128, WstT  + (size_t)b*2*128*128,            128, 7};
    for(int b=0;b<3;b++) p.d[i++] = {Wtw  + (size_t)b*128*128, WstT  + (size_t)b*2*128*128 + 128*128,  128, 7};
    p.d[i++] = {Wout, WoutT, 128, 7};
    wconv_kernel<<<dim3(160,29), 256, 0, stream>>>(p);
  }

  // ---- CSR + geometry ----
  hipMemsetAsync(cnt_ji, 0, (size_t)(E_ + N_)*sizeof(int), stream);
  hist2_kernel<<<(T_+E_)/256, 256, 0, stream>>>(ji, ei + E_, cnt_ji, cnt_dst);
  scanA_kernel<<<68, 256, 0, stream>>>(cnt_ji, cnt_dst, bsum);
  scanB_kernel<<<1, 128, 0, stream>>>(bsum, boff);
  scanC_kernel<<<68, 256, 0, stream>>>(cnt_ji, cnt_dst, boff, off_ji, cur_ji, off_dst, cur_dst);
  pos_kernel<<<N_/256, 256, 0, stream>>>(frac, lengths, angles, pos);
  edge_kernel<<<E_/4, 256, 0, stream>>>(pos, ei, vec, rbf);
  fill2t_kernel<<<(T_+E_)/256, 256, 0, stream>>>(ji, kj, ei + E_, vec, cur_ji, kj_s, cbf_s, cur_dst, list_dst);
  h0_kernel<<<N_, 128, 0, stream>>>(emb, types, noise, Whz, h, hbf);

  for(int b = 0; b < 3; b++){
    const bf16* WmT_b  = WmT   + (size_t)b*128*128;
    const bf16* Wr1T_b = Wr1T  + (size_t)b*128*64;
    const bf16* WdT_b  = WdownT+ (size_t)b*64*128;
    const float* Wc_b  = Wcbf  + (size_t)b*16*64;
    const bf16* WuT_b  = WupT  + (size_t)b*128*64;
    const bf16* WaT_b  = WaT   + (size_t)b*128*128;
    const bf16* Wr2T_b = Wr2T  + (size_t)b*128*64;
    const bf16* WhT_b  = WhT   + (size_t)b*128*128;
    const bf16* WstT_b = WstT  + (size_t)b*2*128*128;

    if(b == 0) dd0_fused<<<E_/128, 256, 0, stream>>>(hbf, rbf, ei, WedgeT, m, WmT_b, Wr1T_b, WdT_b, xbuf);
    else       dd_fused<<<E_/128, 256, 0, stream>>>(m, WmT_b, rbf, Wr1T_b, WdT_b, xbuf, ei, hsb, htb);
    tsum_kernel<<<E_/4, 256, 0, stream>>>(off_ji, kj_s, cbf_s, xbuf, Wc_b, ts);
    if(b < 2) wup_wa<true ><<<E_/128, 256, 0, stream>>>(ts, WuT_b, m, WaT_b, rbf, Wr2T_b, tmp);
    else      wup_wa<false><<<E_/128, 256, 0, stream>>>(ts, WuT_b, m, WaT_b, rbf, Wr2T_b, tmp);
    asum_kernel<<<N_*16/256, 256, 0, stream>>>(off_dst, list_dst, tmp, a);
    if(b < 2) atom_fused<false><<<N_/128, 256, 0, stream>>>(a, WhT_b, h, WstT_b, hsb, htb, WoutT, hW);
    else      atom_fused<true ><<<N_/128, 256, 0, stream>>>(a, WhT_b, h, WstT_b, hsb, htb, WoutT, hW);
  }

  // ---- fused readout ----
  mlp_kernel<<<B_, 256, 0, stream>>>(hW, numat, Wfc0, bfc0, Wfc1, bfc1, Wfc2, bfc2, out);
}

// Round 12
// 599.714 us; speedup vs baseline: 1.1421x; 1.1421x over previous
//
#include <hip/hip_runtime.h>
#include <hip/hip_bf16.h>
#include <math.h>

constexpr int B_ = 128, N_ = 4096, E_ = 65536, T_ = 262144;

typedef __attribute__((ext_vector_type(8))) __bf16 bf16x8;
typedef __attribute__((ext_vector_type(4))) float f32x4;
typedef __hip_bfloat16 bf16;

__device__ __forceinline__ float silu_f(float x){ return x / (1.0f + __expf(-x)); }
__device__ __forceinline__ float bf2f(bf16 v){ return __bfloat162float(v); }
__device__ __forceinline__ bf16  f2bf(float v){ return __float2bfloat16(v); }
__device__ __forceinline__ float bfx(bf16x8 v, int j){ __bf16 t = v[j]; return (float)t; }
__device__ __forceinline__ int   swz(int row, int col){ return col ^ ((row & 7) << 3); }

// ================= CSR build =================
__global__ void hist2_kernel(const int* __restrict__ ji, const int* __restrict__ eidst,
                             int* __restrict__ cnt_ji, int* __restrict__ cnt_dst){
  int i = blockIdx.x*256 + threadIdx.x;
  if(i < T_) atomicAdd(&cnt_ji[ji[i]], 1);
  else       atomicAdd(&cnt_dst[eidst[i - T_]], 1);
}

// fill + tprep fused: triplet lane computes its CSR slot AND the Chebyshev basis (bf16)
__global__ __launch_bounds__(256) void fill2t_kernel(const int* __restrict__ ji, const int* __restrict__ kj,
                                                     const int* __restrict__ eidst, const float* __restrict__ vec,
                                                     int* __restrict__ cur_ji, int* __restrict__ kj_s,
                                                     bf16* __restrict__ cbf_s,
                                                     int* __restrict__ cur_dst, int* __restrict__ list_dst){
  int i = blockIdx.x*256 + threadIdx.x;
  if(i < T_){
    int a = ji[i], b = kj[i];
    int p = atomicAdd(&cur_ji[a], 1);
    kj_s[p] = b;
    float ax = vec[a*3], ay = vec[a*3+1], az = vec[a*3+2];
    float bx = vec[b*3], by = vec[b*3+1], bz = vec[b*3+2];
    float dot = ax*bx + ay*by + az*bz;
    float na = sqrtf(ax*ax + ay*ay + az*az);
    float nb = sqrtf(bx*bx + by*by + bz*bz);
    float x = dot / (na*nb + 1e-9f);
    x = fminf(fmaxf(x, -1.0f + 1e-6f), 1.0f - 1e-6f);
    float c[16];
    c[0] = 1.0f; c[1] = x;
    float x2 = 2.0f * x;
    #pragma unroll
    for(int s = 2; s < 16; s++) c[s] = x2*c[s-1] - c[s-2];
    bf16x8 o0, o1;
    #pragma unroll
    for(int j = 0; j < 8; j++){ o0[j] = (__bf16)c[j]; o1[j] = (__bf16)c[8+j]; }
    *(bf16x8*)&cbf_s[(size_t)p*16]     = o0;
    *(bf16x8*)&cbf_s[(size_t)p*16 + 8] = o1;
  } else {
    int e = i - T_;
    int p = atomicAdd(&cur_dst[eidst[e]], 1);
    list_dst[p] = e;
  }
}

// hierarchical scan: A = per-1024-chunk sums, B = scan chunk sums, C = apply.
__global__ __launch_bounds__(256) void scanA_kernel(const int* __restrict__ cnt_ji, const int* __restrict__ cnt_dst,
                                                    int* __restrict__ bsum){
  int blk = blockIdx.x;
  const int* src = (blk < 64) ? cnt_ji : cnt_dst;
  int base = (blk < 64) ? blk*1024 : (blk - 64)*1024;
  int t = threadIdx.x;
  int4 v = *(const int4*)&src[base + t*4];
  int s = v.x + v.y + v.z + v.w;
  #pragma unroll
  for(int d = 1; d < 64; d <<= 1) s += __shfl_xor(s, d);
  __shared__ int ws[4];
  if((t & 63) == 0) ws[t >> 6] = s;
  __syncthreads();
  if(t == 0) bsum[blk] = ws[0] + ws[1] + ws[2] + ws[3];
}
__global__ __launch_bounds__(128) void scanB_kernel(const int* __restrict__ bsum, int* __restrict__ boff){
  __shared__ int sh[68];
  int t = threadIdx.x;
  if(t < 68) sh[t] = bsum[t];
  __syncthreads();
  if(t == 0){
    int run = 0;
    for(int i = 0; i < 64; i++){ boff[i] = run; run += sh[i]; }
    run = 0;
    for(int i = 64; i < 68; i++){ boff[i] = run; run += sh[i]; }
  }
}
__global__ __launch_bounds__(256) void scanC_kernel(const int* __restrict__ cnt_ji, const int* __restrict__ cnt_dst,
                                                    const int* __restrict__ boff,
                                                    int* __restrict__ off_ji, int* __restrict__ cur_ji,
                                                    int* __restrict__ off_dst, int* __restrict__ cur_dst){
  int blk = blockIdx.x;
  const int* src; int* offs; int* cur; int base;
  if(blk < 64){ src = cnt_ji; offs = off_ji; cur = cur_ji; base = blk*1024; }
  else        { src = cnt_dst; offs = off_dst; cur = cur_dst; base = (blk - 64)*1024; }
  int t = threadIdx.x, lane = t & 63, w = t >> 6;
  int4 v = *(const int4*)&src[base + t*4];
  int s4 = v.x + v.y + v.z + v.w;
  int x = s4;
  #pragma unroll
  for(int d = 1; d < 64; d <<= 1){ int u = __shfl_up(x, d); if(lane >= d) x += u; }
  __shared__ int ws[4];
  if(lane == 63) ws[w] = x;
  __syncthreads();
  int wo = 0;
  for(int i = 0; i < w; i++) wo += ws[i];
  int o0 = boff[blk] + wo + (x - s4);
  int4 oo;
  oo.x = o0; oo.y = o0 + v.x; oo.z = oo.y + v.y; oo.w = oo.z + v.z;
  *(int4*)&offs[base + t*4] = oo;
  *(int4*)&cur[base + t*4]  = oo;
  if(blk == 0 && t == 0){ off_ji[E_] = T_; off_dst[N_] = E_; }
}

// ================= geometry =================
__global__ void pos_kernel(const float* __restrict__ frac, const float* __restrict__ lengths,
                           const float* __restrict__ angles, float* __restrict__ pos){
  int i = blockIdx.x*256 + threadIdx.x;
  if(i >= N_) return;
  int b = i >> 5;
  const float d2r = 0.017453292519943295f;
  float La = lengths[b*3+0], Lb = lengths[b*3+1], Lc = lengths[b*3+2];
  float al = angles[b*3+0]*d2r, be = angles[b*3+1]*d2r, ga = angles[b*3+2]*d2r;
  float ca = cosf(al), cb = cosf(be), cg = cosf(ga), sg = sinf(ga);
  float cx = cb, cy = (ca - cb*cg) / sg;
  float cz = sqrtf(fmaxf(1.0f - cx*cx - cy*cy, 1e-8f));
  float l00 = La, l10 = Lb*cg, l11 = Lb*sg, l20 = Lc*cx, l21 = Lc*cy, l22 = Lc*cz;
  float fx = frac[i*3], fy = frac[i*3+1], fz = frac[i*3+2];
  pos[i*3+0] = fx*l00 + fy*l10 + fz*l20;
  pos[i*3+1] = fy*l11 + fz*l21;
  pos[i*3+2] = fz*l22;
}

__global__ __launch_bounds__(256) void edge_kernel(const float* __restrict__ pos, const int* __restrict__ ei,
                                                   float* __restrict__ vec, bf16* __restrict__ rbf){
  int e = blockIdx.x*4 + (threadIdx.x >> 6);
  int lane = threadIdx.x & 63;
  int s = ei[e], d = ei[E_ + e];
  float vx = pos[d*3+0]-pos[s*3+0];
  float vy = pos[d*3+1]-pos[s*3+1];
  float vz = pos[d*3+2]-pos[s*3+2];
  float dd = sqrtf(vx*vx + vy*vy + vz*vz + 1e-12f);
  float dsc = dd * (1.0f/7.0f);
  float env = 0.0f;
  if(dsc < 1.0f){
    float d2 = dsc*dsc, d5 = d2*d2*dsc;
    env = 1.0f - 21.0f*d5 + 35.0f*d5*dsc - 15.0f*d5*d2;
  }
  float arg = (float)(lane+1) * 3.14159265358979f * dsc;
  rbf[(size_t)e*64 + lane] = f2bf(env * 0.5345224838248488f * sinf(arg) / dd);
  if(lane < 3){ vec[e*3+lane] = (lane==0) ? vx : (lane==1 ? vy : vz); }
}

// ================= weight transpose+convert =================
struct WDesc { const float* src; bf16* dst; int K; int shN; };
struct WPackAll { WDesc d[29]; };
__global__ __launch_bounds__(256) void wconv_kernel(WPackAll p){
  WDesc w = p.d[blockIdx.y];
  int idx = blockIdx.x*256 + threadIdx.x;
  int NN = 1 << w.shN;
  if(idx >= w.K * NN) return;
  int k = idx >> w.shN, c = idx & (NN - 1);
  w.dst[(size_t)c * w.K + k] = f2bf(w.src[idx]);
}

// ================= h init =================
__global__ __launch_bounds__(128) void h0_kernel(const float* __restrict__ emb, const int* __restrict__ types,
                                                 const float* __restrict__ noise, const float* __restrict__ Whz,
                                                 float* __restrict__ h, bf16* __restrict__ hbf){
  __shared__ float arow[129];
  int i = blockIdx.x;
  int c = threadIdx.x;
  arow[c] = emb[(size_t)types[i]*128 + c];
  if(c == 0) arow[128] = noise[i >> 5];
  __syncthreads();
  float acc = 0.f;
  for(int k = 0; k < 129; k++) acc += arow[k] * Whz[(size_t)k*128 + c];
  float v = silu_f(acc);
  h[(size_t)i*128 + c] = v;
  hbf[(size_t)i*128 + c] = f2bf(v);
}

// ================= MFMA cores =================
template<int KK, int FM>
__device__ __forceinline__ void kloop(const bf16* __restrict__ A, const bf16* __restrict__ W,
                                      int rowA0, int colW0, int lr, int lk, f32x4 (*acc)[4])
{
  #pragma unroll
  for(int k0 = 0; k0 < KK; k0 += 32){
    bf16x8 af[FM], bv[4];
    #pragma unroll
    for(int fm = 0; fm < FM; fm++)
      af[fm] = *(const bf16x8*)(A + (size_t)(rowA0 + fm*16 + lr)*KK + k0 + lk*8);
    #pragma unroll
    for(int fn = 0; fn < 4; fn++)
      bv[fn] = *(const bf16x8*)(W + (size_t)(colW0 + fn*16 + lr)*KK + k0 + lk*8);
    #pragma unroll
    for(int fm = 0; fm < FM; fm++)
      #pragma unroll
      for(int fn = 0; fn < 4; fn++)
        acc[fm][fn] = __builtin_amdgcn_mfma_f32_16x16x32_bf16(af[fm], bv[fn], acc[fm][fn], 0, 0, 0);
  }
}

template<int FM>
__device__ __forceinline__ void kloop_lds(const __bf16* sA, const bf16* __restrict__ W,
                                          int rowL0, int colW0, int lr, int lk, f32x4 (*acc)[4])
{
  #pragma unroll
  for(int k0 = 0; k0 < 128; k0 += 32){
    bf16x8 af[FM], bv[4];
    #pragma unroll
    for(int fm = 0; fm < FM; fm++){
      int row = rowL0 + fm*16 + lr;
      af[fm] = *(const bf16x8*)&sA[row*128 + swz(row, k0 + lk*8)];
    }
    #pragma unroll
    for(int fn = 0; fn < 4; fn++)
      bv[fn] = *(const bf16x8*)(W + (size_t)(colW0 + fn*16 + lr)*128 + k0 + lk*8);
    #pragma unroll
    for(int fm = 0; fm < FM; fm++)
      #pragma unroll
      for(int fn = 0; fn < 4; fn++)
        acc[fm][fn] = __builtin_amdgcn_mfma_f32_16x16x32_bf16(af[fm], bv[fn], acc[fm][fn], 0, 0, 0);
  }
}

// shared epilogue piece: dual GEMM over sM + @Wdown, single LDS buffer (in place)
__device__ __forceinline__ void dd_tail(__bf16* sM, const bf16* __restrict__ Wm,
                                        const bf16* __restrict__ rbf, const bf16* __restrict__ Wr1,
                                        const bf16* __restrict__ Wd, bf16* __restrict__ xout,
                                        int row0, int wid, int wr, int wc, int lr, int lk)
{
  f32x4 acc[4][4];
  #pragma unroll
  for(int i = 0; i < 4; i++)
    #pragma unroll
    for(int j = 0; j < 4; j++) acc[i][j] = (f32x4){0.f,0.f,0.f,0.f};
  kloop_lds<4>(sM, Wm, wr*64, wc*64, lr, lk, acc);
  float sv[4][4][4];
  #pragma unroll
  for(int i = 0; i < 4; i++)
    #pragma unroll
    for(int j = 0; j < 4; j++){
      #pragma unroll
      for(int r = 0; r < 4; r++) sv[i][j][r] = silu_f(acc[i][j][r]);
      acc[i][j] = (f32x4){0.f,0.f,0.f,0.f};
    }
  kloop<64,4>(rbf, Wr1, row0 + wr*64, wc*64, lr, lk, acc);
  __syncthreads();               // all GEMM1 LDS reads done before overwrite
  #pragma unroll
  for(int fm = 0; fm < 4; fm++)
    #pragma unroll
    for(int fn = 0; fn < 4; fn++)
      #pragma unroll
      for(int r = 0; r < 4; r++){
        int row = wr*64 + fm*16 + lk*4 + r;
        int col = wc*64 + fn*16 + lr;
        sM[row*128 + swz(row, col)] = (__bf16)(sv[fm][fn][r] * acc[fm][fn][r]);
      }
  __syncthreads();
  // GEMM2: x = tmp @ Wdown
  f32x4 a2[2][4];
  #pragma unroll
  for(int i = 0; i < 2; i++)
    #pragma unroll
    for(int j = 0; j < 4; j++) a2[i][j] = (f32x4){0.f,0.f,0.f,0.f};
  kloop_lds<2>(sM, Wd, wid*32, 0, lr, lk, a2);
  #pragma unroll
  for(int fm = 0; fm < 2; fm++)
    #pragma unroll
    for(int fn = 0; fn < 4; fn++)
      #pragma unroll
      for(int r = 0; r < 4; r++){
        int row = wid*32 + fm*16 + lk*4 + r;
        int col = fn*16 + lr;
        xout[(size_t)(row0 + row)*64 + col] = f2bf(a2[fm][fn][r]);
      }
}

// ===== dd0_fused (b=0): m = silu(concat@Wedge) computed in-kernel, then dual GEMM + @Wdown =====
__global__ __launch_bounds__(256, 2) void dd0_fused(
    const bf16* __restrict__ hb, const bf16* __restrict__ rbf, const int* __restrict__ ei,
    const bf16* __restrict__ We /*[128][320]*/, bf16* __restrict__ m,
    const bf16* __restrict__ Wm, const bf16* __restrict__ Wr1,
    const bf16* __restrict__ Wd, bf16* __restrict__ xout)
{
  __shared__ __bf16 sM[128*128];
  const int tid = threadIdx.x;
  const int wid = tid >> 6, lane = tid & 63;
  const int wr = wid >> 1, wc = wid & 1;
  const int lr = lane & 15, lk = lane >> 4;
  const int row0 = blockIdx.x*128;
  const int e0 = row0 + wr*64;

  int esrc[4], edst[4];
  #pragma unroll
  for(int fm = 0; fm < 4; fm++){
    int e = e0 + fm*16 + lr;
    esrc[fm] = ei[e]; edst[fm] = ei[E_ + e];
  }
  f32x4 acc[4][4];
  #pragma unroll
  for(int i = 0; i < 4; i++)
    #pragma unroll
    for(int j = 0; j < 4; j++) acc[i][j] = (f32x4){0.f,0.f,0.f,0.f};
  #pragma unroll
  for(int ks = 0; ks < 10; ks++){
    const int k0 = ks*32;
    bf16x8 af[4], bv[4];
    #pragma unroll
    for(int fm = 0; fm < 4; fm++){
      const bf16* p;
      if(k0 < 128)      p = hb + (size_t)esrc[fm]*128 + k0;
      else if(k0 < 256) p = hb + (size_t)edst[fm]*128 + (k0 - 128);
      else              p = rbf + (size_t)(e0 + fm*16 + lr)*64 + (k0 - 256);
      af[fm] = *(const bf16x8*)(p + lk*8);
    }
    #pragma unroll
    for(int fn = 0; fn < 4; fn++)
      bv[fn] = *(const bf16x8*)(We + (size_t)(wc*64 + fn*16 + lr)*320 + k0 + lk*8);
    #pragma unroll
    for(int fm = 0; fm < 4; fm++)
      #pragma unroll
      for(int fn = 0; fn < 4; fn++)
        acc[fm][fn] = __builtin_amdgcn_mfma_f32_16x16x32_bf16(af[fm], bv[fn], acc[fm][fn], 0, 0, 0);
  }
  #pragma unroll
  for(int fm = 0; fm < 4; fm++)
    #pragma unroll
    for(int fn = 0; fn < 4; fn++)
      #pragma unroll
      for(int r = 0; r < 4; r++){
        int row = wr*64 + fm*16 + lk*4 + r;
        int col = wc*64 + fn*16 + lr;
        bf16 v = f2bf(silu_f(acc[fm][fn][r]));
        m[(size_t)(row0 + row)*128 + col] = v;
        sM[row*128 + swz(row, col)] = (__bf16)bf2f(v);
      }
  __syncthreads();
  dd_tail(sM, Wm, rbf, Wr1, Wd, xout, row0, wid, wr, wc, lr, lk);
}

// ===== dd_fused (b>=1): scat + dual GEMM + @Wdown, single LDS buffer =====
__global__ __launch_bounds__(256, 2) void dd_fused(
    bf16* __restrict__ m, const bf16* __restrict__ Wm,
    const bf16* __restrict__ rbf, const bf16* __restrict__ Wr1,
    const bf16* __restrict__ Wd, bf16* __restrict__ xout,
    const int* __restrict__ ei, const bf16* __restrict__ hs, const bf16* __restrict__ ht)
{
  __shared__ __bf16 sM[128*128];
  const int tid = threadIdx.x;
  const int wid = tid >> 6, lane = tid & 63;
  const int wr = wid >> 1, wc = wid & 1;
  const int lr = lane & 15, lk = lane >> 4;
  const int row0 = blockIdx.x*128;

  {
    int r = tid >> 1, c0 = (tid & 1)*64;
    int e = row0 + r;
    int s = ei[e], d = ei[E_ + e];
    #pragma unroll
    for(int j = 0; j < 8; j++){
      int col = c0 + j*8;
      bf16x8 vm = *(const bf16x8*)&m[(size_t)e*128 + col];
      bf16x8 va = *(const bf16x8*)&hs[(size_t)s*128 + col];
      bf16x8 vb = *(const bf16x8*)&ht[(size_t)d*128 + col];
      #pragma unroll
      for(int q = 0; q < 8; q++) vm[q] = (__bf16)(bfx(vm,q) + silu_f(bfx(va,q) + bfx(vb,q)));
      *(bf16x8*)&m[(size_t)e*128 + col] = vm;
      *(bf16x8*)&sM[r*128 + swz(r, col)] = vm;
    }
  }
  __syncthreads();
  dd_tail(sM, Wm, rbf, Wr1, Wd, xout, row0, wid, wr, wc, lr, lk);
}

// ===== wup_wa: m += silu(ts@Wup); tmp = silu(m@Wa)*(rbf@Wr2) — single LDS buffer =====
template<bool WRITEM>
__global__ __launch_bounds__(256, 2) void wup_wa(
    const bf16* __restrict__ ts, const bf16* __restrict__ Wu,
    bf16* __restrict__ m, const bf16* __restrict__ Wa,
    const bf16* __restrict__ rbf, const bf16* __restrict__ Wr2,
    bf16* __restrict__ tmp)
{
  __shared__ __bf16 sB[128*128];
  const int tid = threadIdx.x;
  const int wid = tid >> 6, lane = tid & 63;
  const int wr = wid >> 1, wc = wid & 1;
  const int lr = lane & 15, lk = lane >> 4;
  const int row0 = blockIdx.x*128;

  {
    int r = tid >> 1, c0 = (tid & 1)*64;
    #pragma unroll
    for(int j = 0; j < 8; j++){
      int col = c0 + j*8;
      bf16x8 vm = *(const bf16x8*)&m[(size_t)(row0 + r)*128 + col];
      *(bf16x8*)&sB[r*128 + swz(r, col)] = vm;
    }
  }
  __syncthreads();

  f32x4 acc[4][4];
  #pragma unroll
  for(int i = 0; i < 4; i++)
    #pragma unroll
    for(int j = 0; j < 4; j++) acc[i][j] = (f32x4){0.f,0.f,0.f,0.f};
  kloop<64,4>(ts, Wu, row0 + wr*64, wc*64, lr, lk, acc);

  // u = m + silu(.): in-place (each thread owns its (row,col) slots)
  #pragma unroll
  for(int fm = 0; fm < 4; fm++)
    #pragma unroll
    for(int fn = 0; fn < 4; fn++)
      #pragma unroll
      for(int r = 0; r < 4; r++){
        int row = wr*64 + fm*16 + lk*4 + r;
        int col = wc*64 + fn*16 + lr;
        float x = (float)sB[row*128 + swz(row, col)] + silu_f(acc[fm][fn][r]);
        if(WRITEM) m[(size_t)(row0 + row)*128 + col] = f2bf(x);
        sB[row*128 + swz(row, col)] = (__bf16)x;
      }
  __syncthreads();

  #pragma unroll
  for(int i = 0; i < 4; i++)
    #pragma unroll
    for(int j = 0; j < 4; j++) acc[i][j] = (f32x4){0.f,0.f,0.f,0.f};
  kloop_lds<4>(sB, Wa, wr*64, wc*64, lr, lk, acc);
  float sv[4][4][4];
  #pragma unroll
  for(int i = 0; i < 4; i++)
    #pragma unroll
    for(int j = 0; j < 4; j++){
      #pragma unroll
      for(int r = 0; r < 4; r++) sv[i][j][r] = silu_f(acc[i][j][r]);
      acc[i][j] = (f32x4){0.f,0.f,0.f,0.f};
    }
  kloop<64,4>(rbf, Wr2, row0 + wr*64, wc*64, lr, lk, acc);
  #pragma unroll
  for(int fm = 0; fm < 4; fm++)
    #pragma unroll
    for(int fn = 0; fn < 4; fn++)
      #pragma unroll
      for(int r = 0; r < 4; r++){
        int row = wr*64 + fm*16 + lk*4 + r;
        int col = wc*64 + fn*16 + lr;
        tmp[(size_t)(row0 + row)*128 + col] = f2bf(sv[fm][fn][r] * acc[fm][fn][r]);
      }
}

// ===== atom_fused: h += silu(a@Wh); then hs/ht (or hW on last iter) =====
template<bool LAST>
__global__ __launch_bounds__(256, 2) void atom_fused(
    const bf16* __restrict__ a, const bf16* __restrict__ Wh,
    float* __restrict__ h,
    const bf16* __restrict__ Wst, bf16* __restrict__ hs, bf16* __restrict__ ht,
    const bf16* __restrict__ Wo, float* __restrict__ hW)
{
  __shared__ __bf16 sH[128*128];
  const int tid = threadIdx.x;
  const int wid = tid >> 6, lane = tid & 63;
  const int wr = wid >> 1, wc = wid & 1;
  const int lr = lane & 15, lk = lane >> 4;
  const int row0 = blockIdx.x*128;

  f32x4 acc[4][4];
  #pragma unroll
  for(int i = 0; i < 4; i++)
    #pragma unroll
    for(int j = 0; j < 4; j++) acc[i][j] = (f32x4){0.f,0.f,0.f,0.f};
  kloop<128,4>(a, Wh, row0 + wr*64, wc*64, lr, lk, acc);

  #pragma unroll
  for(int fm = 0; fm < 4; fm++)
    #pragma unroll
    for(int fn = 0; fn < 4; fn++)
      #pragma unroll
      for(int r = 0; r < 4; r++){
        int row = wr*64 + fm*16 + lk*4 + r;
        int col = wc*64 + fn*16 + lr;
        size_t off = (size_t)(row0 + row)*128 + col;
        float x = h[off] + silu_f(acc[fm][fn][r]);
        h[off] = x;
        sH[row*128 + swz(row, col)] = (__bf16)x;
      }
  __syncthreads();

  if(!LAST){
    #pragma unroll
    for(int i = 0; i < 4; i++)
      #pragma unroll
      for(int j = 0; j < 4; j++) acc[i][j] = (f32x4){0.f,0.f,0.f,0.f};
    kloop_lds<4>(sH, Wst, wr*64, wc*64, lr, lk, acc);
    #pragma unroll
    for(int fm = 0; fm < 4; fm++)
      #pragma unroll
      for(int fn = 0; fn < 4; fn++)
        #pragma unroll
        for(int r = 0; r < 4; r++){
          int row = wr*64 + fm*16 + lk*4 + r;
          int col = wc*64 + fn*16 + lr;
          hs[(size_t)(row0 + row)*128 + col] = f2bf(acc[fm][fn][r]);
        }
    #pragma unroll
    for(int i = 0; i < 4; i++)
      #pragma unroll
      for(int j = 0; j < 4; j++) acc[i][j] = (f32x4){0.f,0.f,0.f,0.f};
    kloop_lds<4>(sH, Wst + 128*128, wr*64, wc*64, lr, lk, acc);
    #pragma unroll
    for(int fm = 0; fm < 4; fm++)
      #pragma unroll
      for(int fn = 0; fn < 4; fn++)
        #pragma unroll
        for(int r = 0; r < 4; r++){
          int row = wr*64 + fm*16 + lk*4 + r;
          int col = wc*64 + fn*16 + lr;
          ht[(size_t)(row0 + row)*128 + col] = f2bf(acc[fm][fn][r]);
        }
  } else {
    #pragma unroll
    for(int i = 0; i < 4; i++)
      #pragma unroll
      for(int j = 0; j < 4; j++) acc[i][j] = (f32x4){0.f,0.f,0.f,0.f};
    kloop_lds<4>(sH, Wo, wr*64, wc*64, lr, lk, acc);
    #pragma unroll
    for(int fm = 0; fm < 4; fm++)
      #pragma unroll
      for(int fn = 0; fn < 4; fn++)
        #pragma unroll
        for(int r = 0; r < 4; r++){
          int row = wr*64 + fm*16 + lk*4 + r;
          int col = wc*64 + fn*16 + lr;
          hW[(size_t)(row0 + row)*128 + col] = acc[fm][fn][r];
        }
  }
}

// ================= triplet segsum (round-7 form: simple loop, bf16 cbf) =================
__global__ __launch_bounds__(256) void tsum_kernel(const int* __restrict__ offs, const int* __restrict__ kj_s,
                                                   const bf16* __restrict__ cbf_s, const bf16* __restrict__ x,
                                                   const float* __restrict__ Wc, bf16* __restrict__ ts){
  int e = blockIdx.x*4 + (threadIdx.x >> 6);
  int lane = threadIdx.x & 63;
  float wcv[16];
  #pragma unroll
  for(int s = 0; s < 16; s++) wcv[s] = Wc[s*64 + lane];
  float acc = 0.f;
  int b0 = offs[e], b1 = offs[e+1];
  for(int idx = b0; idx < b1; ++idx){
    int k = kj_s[idx];
    bf16x8 c0 = *(const bf16x8*)&cbf_s[(size_t)idx*16];
    bf16x8 c1 = *(const bf16x8*)&cbf_s[(size_t)idx*16 + 8];
    float cw = 0.f;
    #pragma unroll
    for(int j = 0; j < 8; j++) cw += bfx(c0,j)*wcv[j] + bfx(c1,j)*wcv[8+j];
    acc += bf2f(x[(size_t)k*64 + lane]) * cw;
  }
  ts[(size_t)e*64 + lane] = f2bf(acc);
}

// ================= edge->atom segsum =================
__global__ __launch_bounds__(256) void asum_kernel(const int* __restrict__ offs, const int* __restrict__ list,
                                                   const bf16* __restrict__ buf, bf16* __restrict__ a){
  int g = blockIdx.x*256 + threadIdx.x;
  int i = g >> 4, c8 = g & 15;
  float acc[8];
  #pragma unroll
  for(int j = 0; j < 8; j++) acc[j] = 0.f;
  int b0 = offs[i], b1 = offs[i+1];
  for(int idx = b0; idx < b1; ++idx){
    bf16x8 v = *(const bf16x8*)&buf[(size_t)list[idx]*128 + c8*8];
    #pragma unroll
    for(int j = 0; j < 8; j++) acc[j] += bfx(v,j);
  }
  bf16x8 o;
  #pragma unroll
  for(int j = 0; j < 8; j++) o[j] = (__bf16)acc[j];
  *(bf16x8*)&a[(size_t)i*128 + c8*8] = o;
}

// ================= fused readout MLP =================
__global__ __launch_bounds__(256) void mlp_kernel(const float* __restrict__ hW, const int* __restrict__ numat,
    const float* __restrict__ W0, const float* __restrict__ b0,
    const float* __restrict__ W1, const float* __restrict__ b1,
    const float* __restrict__ W2, const float* __restrict__ b2,
    float* __restrict__ out)
{
  __shared__ float zs[128], x0[256], x1[256];
  int b = blockIdx.x, t = threadIdx.x;
  if(t < 128){
    float s = 0.f;
    #pragma unroll 4
    for(int i = 0; i < 32; i++) s += hW[((size_t)(b*32 + i))*128 + t];
    zs[t] = s / (float)numat[b];
  }
  __syncthreads();
  {
    float acc = b0[t];
    for(int k = 0; k < 128; k++) acc += zs[k] * W0[(size_t)k*256 + t];
    x0[t] = fmaxf(acc, 0.f);
  }
  __syncthreads();
  {
    float acc = b1[t];
    for(int k = 0; k < 256; k++) acc += x0[k] * W1[(size_t)k*256 + t];
    x1[t] = fmaxf(acc, 0.f);
  }
  __syncthreads();
  if(t < 230){
    float acc = b2[t];
    for(int k = 0; k < 256; k++) acc += x1[k] * W2[(size_t)k*230 + t];
    out[(size_t)b*230 + t] = acc;
  }
}

extern "C" void kernel_launch(void* const* d_in, const int* in_sizes, int n_in,
                              void* d_out, int out_size, void* d_ws, size_t ws_size,
                              hipStream_t stream)
{
  const float* noise   = (const float*)d_in[0];
  const float* frac    = (const float*)d_in[1];
  const float* lengths = (const float*)d_in[2];
  const float* angles  = (const float*)d_in[3];
  const int*   types   = (const int*)d_in[4];
  const int*   numat   = (const int*)d_in[5];
  const int*   ei      = (const int*)d_in[6];
  const int*   ji      = (const int*)d_in[7];
  const int*   kj      = (const int*)d_in[8];
  const float* emb     = (const float*)d_in[9];
  const float* Whz     = (const float*)d_in[10];
  const float* Wedge   = (const float*)d_in[11];
  const float* Wm      = (const float*)d_in[12];
  const float* Wr1     = (const float*)d_in[13];
  const float* Wdown   = (const float*)d_in[14];
  const float* Wcbf    = (const float*)d_in[15];
  const float* Wup     = (const float*)d_in[16];
  const float* Wa      = (const float*)d_in[17];
  const float* Wr2     = (const float*)d_in[18];
  const float* Wh      = (const float*)d_in[19];
  const float* Wsw     = (const float*)d_in[20];
  const float* Wtw     = (const float*)d_in[21];
  const float* Wout    = (const float*)d_in[22];
  const float* Wfc0    = (const float*)d_in[23];
  const float* bfc0    = (const float*)d_in[24];
  const float* Wfc1    = (const float*)d_in[25];
  const float* bfc1    = (const float*)d_in[26];
  const float* Wfc2    = (const float*)d_in[27];
  const float* bfc2    = (const float*)d_in[28];
  float* out = (float*)d_out;

  char* base = (char*)d_ws;
  size_t oo = 0;
  auto ab = [&](size_t bytes)->void*{ void* p = base + oo; oo += bytes; oo = (oo + 63) & ~(size_t)63; return p; };

  float* pos   = (float*)ab((size_t)N_*3*4);
  float* vec   = (float*)ab((size_t)E_*3*4);
  bf16*  rbf   = (bf16*) ab((size_t)E_*64*2);
  bf16*  cbf_s = (bf16*) ab((size_t)T_*16*2);
  int*   kj_s  = (int*)  ab((size_t)T_*4);
  float* h     = (float*)ab((size_t)N_*128*4);
  bf16*  hbf   = (bf16*) ab((size_t)N_*128*2);
  bf16*  m     = (bf16*) ab((size_t)E_*128*2);
  bf16*  tmp   = (bf16*) ab((size_t)E_*128*2);
  bf16*  ts    = (bf16*) ab((size_t)E_*64*2);
  bf16*  xbuf  = (bf16*) ab((size_t)E_*64*2);
  bf16*  a     = (bf16*) ab((size_t)N_*128*2);
  bf16*  hsb   = (bf16*) ab((size_t)N_*128*2);
  bf16*  htb   = (bf16*) ab((size_t)N_*128*2);
  float* hW    = (float*)ab((size_t)N_*128*4);

  bf16* WedgeT = (bf16*)ab(320*128*2);
  bf16* WmT    = (bf16*)ab((size_t)3*128*128*2);
  bf16* Wr1T   = (bf16*)ab((size_t)3*128*64*2);
  bf16* WdownT = (bf16*)ab((size_t)3*64*128*2);
  bf16* WupT   = (bf16*)ab((size_t)3*128*64*2);
  bf16* WaT    = (bf16*)ab((size_t)3*128*128*2);
  bf16* Wr2T   = (bf16*)ab((size_t)3*128*64*2);
  bf16* WhT    = (bf16*)ab((size_t)3*128*128*2);
  bf16* WstT   = (bf16*)ab((size_t)3*2*128*128*2);
  bf16* WoutT  = (bf16*)ab(128*128*2);

  int* cnt_ji   = (int*)ab((size_t)(E_ + N_)*4);
  int* cnt_dst  = cnt_ji + E_;
  int* off_ji   = (int*)ab((size_t)(E_+1)*4);
  int* cur_ji   = (int*)ab((size_t)E_*4);
  int* off_dst  = (int*)ab((size_t)(N_+1)*4);
  int* cur_dst  = (int*)ab((size_t)N_*4);
  int* list_dst = (int*)ab((size_t)E_*4);
  int* bsum     = (int*)ab(68*4);
  int* boff     = (int*)ab(68*4);

  // ---- weight conversion (single dispatch) ----
  WPackAll p{};
  {
    int i = 0;
    p.d[i++] = {Wedge, WedgeT, 320, 7};
    for(int b=0;b<3;b++) p.d[i++] = {Wm   + (size_t)b*128*128, WmT   + (size_t)b*128*128, 128, 7};
    for(int b=0;b<3;b++) p.d[i++] = {Wr1  + (size_t)b*64*128,  Wr1T  + (size_t)b*128*64,   64, 7};
    for(int b=0;b<3;b++) p.d[i++] = {Wdown+ (size_t)b*128*64,  WdownT+ (size_t)b*64*128,  128, 6};
    for(int b=0;b<3;b++) p.d[i++] = {Wup  + (size_t)b*64*128,  WupT  + (size_t)b*128*64,   64, 7};
    for(int b=0;b<3;b++) p.d[i++] = {Wa   + (size_t)b*128*128, WaT   + (size_t)b*128*128, 128, 7};
    for(int b=0;b<3;b++) p.d[i++] = {Wr2  + (size_t)b*64*128,  Wr2T  + (size_t)b*128*64,   64, 7};
    for(int b=0;b<3;b++) p.d[i++] = {Wh   + (size_t)b*128*128, WhT   + (size_t)b*128*128, 128, 7};
    for(int b=0;b<3;b++) p.d[i++] = {Wsw  + (size_t)b*128*128, WstT  + (size_t)b*2*128*128,            128, 7};
    for(int b=0;b<3;b++) p.d[i++] = {Wtw  + (size_t)b*128*128, WstT  + (size_t)b*2*128*128 + 128*128,  128, 7};
    p.d[i++] = {Wout, WoutT, 128, 7};
    wconv_kernel<<<dim3(160,29), 256, 0, stream>>>(p);
  }

  // ---- CSR + geometry ----
  hipMemsetAsync(cnt_ji, 0, (size_t)(E_ + N_)*sizeof(int), stream);
  hist2_kernel<<<(T_+E_)/256, 256, 0, stream>>>(ji, ei + E_, cnt_ji, cnt_dst);
  scanA_kernel<<<68, 256, 0, stream>>>(cnt_ji, cnt_dst, bsum);
  scanB_kernel<<<1, 128, 0, stream>>>(bsum, boff);
  scanC_kernel<<<68, 256, 0, stream>>>(cnt_ji, cnt_dst, boff, off_ji, cur_ji, off_dst, cur_dst);
  pos_kernel<<<N_/256, 256, 0, stream>>>(frac, lengths, angles, pos);
  edge_kernel<<<E_/4, 256, 0, stream>>>(pos, ei, vec, rbf);
  fill2t_kernel<<<(T_+E_)/256, 256, 0, stream>>>(ji, kj, ei + E_, vec, cur_ji, kj_s, cbf_s, cur_dst, list_dst);
  h0_kernel<<<N_, 128, 0, stream>>>(emb, types, noise, Whz, h, hbf);

  for(int b = 0; b < 3; b++){
    const bf16* WmT_b  = WmT   + (size_t)b*128*128;
    const bf16* Wr1T_b = Wr1T  + (size_t)b*128*64;
    const bf16* WdT_b  = WdownT+ (size_t)b*64*128;
    const float* Wc_b  = Wcbf  + (size_t)b*16*64;
    const bf16* WuT_b  = WupT  + (size_t)b*128*64;
    const bf16* WaT_b  = WaT   + (size_t)b*128*128;
    const bf16* Wr2T_b = Wr2T  + (size_t)b*128*64;
    const bf16* WhT_b  = WhT   + (size_t)b*128*128;
    const bf16* WstT_b = WstT  + (size_t)b*2*128*128;

    if(b == 0) dd0_fused<<<E_/128, 256, 0, stream>>>(hbf, rbf, ei, WedgeT, m, WmT_b, Wr1T_b, WdT_b, xbuf);
    else       dd_fused<<<E_/128, 256, 0, stream>>>(m, WmT_b, rbf, Wr1T_b, WdT_b, xbuf, ei, hsb, htb);
    tsum_kernel<<<E_/4, 256, 0, stream>>>(off_ji, kj_s, cbf_s, xbuf, Wc_b, ts);
    if(b < 2) wup_wa<true ><<<E_/128, 256, 0, stream>>>(ts, WuT_b, m, WaT_b, rbf, Wr2T_b, tmp);
    else      wup_wa<false><<<E_/128, 256, 0, stream>>>(ts, WuT_b, m, WaT_b, rbf, Wr2T_b, tmp);
    asum_kernel<<<N_*16/256, 256, 0, stream>>>(off_dst, list_dst, tmp, a);
    if(b < 2) atom_fused<false><<<N_/128, 256, 0, stream>>>(a, WhT_b, h, WstT_b, hsb, htb, WoutT, hW);
    else      atom_fused<true ><<<N_/128, 256, 0, stream>>>(a, WhT_b, h, WstT_b, hsb, htb, WoutT, hW);
  }

  // ---- fused readout ----
  mlp_kernel<<<B_, 256, 0, stream>>>(hW, numat, Wfc0, bfc0, Wfc1, bfc1, Wfc2, bfc2, out);
}